// Round 2
// baseline (188.390 us; speedup 1.0000x reference)
//
#include <hip/hip_runtime.h>
#include <math.h>

#define NPTS 16384
#define KN 32
#define C 256
#define NQ 8192              // 8 * 1024 queries
#define PF_ELEMS (NQ * C)

#define W1P_ELEMS (3 * 16 * 64 * 8)                 // 24576  (Ktiles=3, Ntiles=16)
#define W2P_ELEMS (8 * 16 * 64 * 8)                 // 65536  (Ktiles=8)
#define WP_ELEMS  (W1P_ELEMS + W2P_ELEMS)           // 90112 halves = 180224 B (16-aligned)
#define HSTR 264                                    // halves per H16 row

typedef _Float16 half8 __attribute__((ext_vector_type(8)));
typedef _Float16 half4v __attribute__((ext_vector_type(4)));
typedef _Float16 half2t __attribute__((ext_vector_type(2)));
typedef float f32x4 __attribute__((ext_vector_type(4)));

union H8u { half8 v; half2t h2[4]; };

__device__ __forceinline__ float fdot2f(half2t a, half2t b, float c) {
#if __has_builtin(__builtin_amdgcn_fdot2)
    return __builtin_amdgcn_fdot2(a, b, c, false);
#else
    return fmaf((float)a[1], (float)b[1], fmaf((float)a[0], (float)b[0], c));
#endif
}

// tanh-approx GeLU: max err ~3e-4.  y = x - x/(e^{2u}+1)
__device__ __forceinline__ float gelu_tanh(float x) {
    const float t  = x * x;
    const float p2 = fmaf(t, 0.0713548162726f, 1.59576912161f);
    const float e  = __expf(x * p2);
    return x - x * __builtin_amdgcn_rcpf(e + 1.0f);
}

__device__ __forceinline__ void stat8(const H8u& u, half2t ones, float& s, float& s2) {
    #pragma unroll
    for (int j = 0; j < 4; ++j) {
        s  = fdot2f(u.h2[j], ones, s);
        s2 = fdot2f(u.h2[j], u.h2[j], s2);
    }
}

__device__ __forceinline__ void norm_gelu8(H8u& u, const H8u& g, const H8u& be,
                                           half2t rsh, half2t nmuh) {
    #pragma unroll
    for (int j = 0; j < 4; ++j) {
        const half2t A = g.h2[j] * rsh;
        const half2t B = A * nmuh + be.h2[j];
        const half2t y = u.h2[j] * A + B;
        half2t o;
        o[0] = (_Float16)gelu_tanh((float)y[0]);
        o[1] = (_Float16)gelu_tanh((float)y[1]);
        u.h2[j] = o;
    }
}

__device__ __forceinline__ void norm8(H8u& u, const H8u& g, const H8u& be,
                                      half2t rsh, half2t nmuh) {
    #pragma unroll
    for (int j = 0; j < 4; ++j) {
        const half2t A = g.h2[j] * rsh;
        const half2t B = A * nmuh + be.h2[j];
        u.h2[j] = u.h2[j] * A + B;
    }
}

// ---------------------------------------------------------------------------
// Prep: pack W1 (91x256 + b1 folded at k=91, K-padded to 96) and W2 (256x256)
// into f16 fragment order; additionally pack xyz into float4 (x,y,z,|p|^2)
// with |p|^2 computed with the EXACT rounding sequence the encoder's ball
// query uses (hoisted, bit-identical membership).
//   flat = ((kt*16 + nt)*64 + lane)*8 + j
//   k = kt*32 + (lane>>4)*8 + j ;  ch = nt*16 + (lane&15)
// ---------------------------------------------------------------------------
__global__ void prep_kernel(const float* __restrict__ W1,
                            const float* __restrict__ b1,
                            const float* __restrict__ W2,
                            const float* __restrict__ xyz,
                            _Float16* __restrict__ wp,
                            float4* __restrict__ xyzw) {
    const int idx = blockIdx.x * 256 + threadIdx.x;   // 0 .. 221183
    if (idx < 96 * 256) {
        const int k = idx >> 8, n = idx & 255;
        const float v = (k < 91) ? W1[k * 256 + n] : ((k == 91) ? b1[n] : 0.0f);
        const int kt = k >> 5, quad = (k >> 3) & 3, j = k & 7;
        const int nt = n >> 4, l15 = n & 15;
        wp[(((kt * 16 + nt) * 64) + quad * 16 + l15) * 8 + j] = (_Float16)v;
    } else if (idx < WP_ELEMS) {
        const int e = idx - 96 * 256;
        const int k = e >> 8, n = e & 255;
        const int kt = k >> 5, quad = (k >> 3) & 3, j = k & 7;
        const int nt = n >> 4, l15 = n & 15;
        wp[W1P_ELEMS + (((kt * 16 + nt) * 64) + quad * 16 + l15) * 8 + j] =
            (_Float16)W2[k * 256 + n];
    } else {
        const int pi = idx - WP_ELEMS;                // 0 .. 131071 (8*16384)
        const float px = xyz[pi * 3 + 0];
        const float py = xyz[pi * 3 + 1];
        const float pz = xyz[pi * 3 + 2];
        const float sp = __fadd_rn(__fadd_rn(__fmul_rn(px, px), __fmul_rn(py, py)),
                                   __fmul_rn(pz, pz));
        xyzw[pi] = make_float4(px, py, pz, sp);
    }
}

// ---------------------------------------------------------------------------
// Fused: ball-query + gather/posenc + MLP1(LN,GeLU) + MLP2(LN) + max.
// Round-15 (session R2): occupancy round.
//  * R1 post-mortem: VALU cuts landed (VALUBusy 59->55.5) but wall flat ->
//    kernel is latency/occupancy-bound. VGPR_Count is now 40 (the (256,6)
//    bound was sized for the 85-reg era) -> stale cap.
//  * __launch_bounds__(256,8): 8 blocks/CU, 32 waves/CU (VGPR cap 64 >= 40,
//    no codegen perturbation expected).
//  * Xs/H16 re-overlaid (round-13 scheme) to get LDS back to 19456 B so
//    8 blocks fit (160KB / 19.45KB = 8.2). Re-pays the fence barrier
//    after GEMM1 (all Xs B-reads done before H16 C-stores).
//  * Keeps all R1 VALU cuts: saddr weight loads (readfirstlane base),
//    packed (x,y,z,|p|^2) ball query, branchless revolution-domain posenc.
// No runtime-indexed private arrays (round-3 lesson).
// ---------------------------------------------------------------------------
__global__ void __launch_bounds__(256, 8)
encoder_fused(const float4* __restrict__ xyzw,
              const float* __restrict__ pf,
              const float* __restrict__ ctr,
              const float* __restrict__ g1, const float* __restrict__ be1,
              const float* __restrict__ b2, const float* __restrict__ g2,
              const float* __restrict__ be2,
              const _Float16* __restrict__ w1p,
              const _Float16* __restrict__ w2p,
              float* __restrict__ out0,      // patch_feature [8192][256]
              float* __restrict__ out1) {    // neighbor idx as float [8192][32]
    const int q = blockIdx.x;
    const int b = q >> 10;
    const int t = threadIdx.x;
    const int w = t >> 6;
    const int lane = t & 63;
    const int quad = lane >> 4;
    const int l15  = lane & 15;

    // Overlaid region: Xs f16[32][104] (phase1 -> GEMM1) then H16 f16[32][264]
    // (C-store -> phase 6). Transition fenced by the barrier after GEMM1.
    __shared__ __align__(16) unsigned char H16raw[KN * HSTR * 2];  // 16896
    __shared__ __align__(16) _Float16 lnph[4 * 256];               // 2048: g1,be1,g2,be2
    __shared__ int nbr[KN];
    __shared__ int wcnt[2][4];

    _Float16 (*H16)[HSTR] = (_Float16(*)[HSTR])H16raw;
    _Float16 (*Xs)[104]   = (_Float16(*)[104])H16raw;   // OVERLAY
    _Float16* g1h  = lnph;
    _Float16* be1h = lnph + 256;
    _Float16* g2h  = lnph + 512;
    _Float16* be2h = lnph + 768;

    lnph[t]       = (_Float16)g1[t];
    lnph[256 + t] = (_Float16)be1[t];
    lnph[512 + t] = (_Float16)g2[t];
    lnph[768 + t] = (_Float16)be2[t];

    // ---- Phase 0: ball query (block-wide ordered compaction) ----
    // first-32-ascending == reference sort+slice; exact unfused fp32 formula
    // (|p|^2 precomputed in prep with the same rounding -> identical bits).
    const float4* xwb = xyzw + (size_t)b * NPTS;
    const float cx = ctr[q * 3 + 0];
    const float cy = ctr[q * 3 + 1];
    const float cz = ctr[q * 3 + 2];
    const float sc = __fadd_rn(__fadd_rn(__fmul_rn(cx, cx), __fmul_rn(cy, cy)),
                               __fmul_rn(cz, cz));

    int found = 0;
    int par = 0;
    for (int base = 0; base < NPTS; base += 256) {
        const int n = base + t;
        const float4 pw = xwb[n];
        const float dt = __fadd_rn(__fadd_rn(__fmul_rn(cx, pw.x), __fmul_rn(cy, pw.y)),
                                   __fmul_rn(cz, pw.z));
        const float sqr = __fsub_rn(__fadd_rn(sc, pw.w), __fmul_rn(2.0f, dt));
        const bool inball = (sqr <= 0.0625f);

        const unsigned long long m = __ballot(inball);
        if (lane == 0) wcnt[par][w] = (int)__popcll(m);
        __syncthreads();
        int pre = found;
        if (w > 0) pre += wcnt[par][0];
        if (w > 1) pre += wcnt[par][1];
        if (w > 2) pre += wcnt[par][2];
        const int tot = found + wcnt[par][0] + wcnt[par][1] + wcnt[par][2] + wcnt[par][3];
        const int pos = pre + (int)__popcll(m & ((1ull << lane) - 1ull));
        if (inball && pos < KN) nbr[pos] = n;
        found = tot;                  // block-uniform
        par ^= 1;
        if (found >= KN) break;
    }
    __syncthreads();                  // nbr visible to all
    const int count = (found < KN) ? found : KN;
    const int first = (count > 0) ? nbr[0] : NPTS;

    if (t < KN)
        out1[(size_t)q * KN + t] = (float)((t < count) ? nbr[t] : first);

    // ---- Phase 1: gather + rel + posenc into Xs (f16; k=91 is 1.0 for b1) ----
    {
        const int k  = t >> 3;
        const int tc = t & 7;
        const int nidx = (k < count) ? nbr[k] : first;
        const int n = (nidx < NPTS) ? nidx : NPTS - 1;   // JAX OOB gather clamp
        const float4 pw = xwb[n];
        const float rx = pw.x - cx;
        const float ry = pw.y - cy;
        const float rz = pw.z - cz;
        const float* pfr = pf + ((size_t)b * NPTS + n) * 64;

        const float4 f0 = *(const float4*)(pfr + tc * 8);
        const float4 f1 = *(const float4*)(pfr + tc * 8 + 4);
        half8 hv;
        hv[0] = (_Float16)f0.x; hv[1] = (_Float16)f0.y;
        hv[2] = (_Float16)f0.z; hv[3] = (_Float16)f0.w;
        hv[4] = (_Float16)f1.x; hv[5] = (_Float16)f1.y;
        hv[6] = (_Float16)f1.z; hv[7] = (_Float16)f1.w;
        *(half8*)&Xs[k][tc * 8] = hv;

        // branchless posenc: ch c = 64+cm; cm<3 -> raw rel; 3<=cm<27 ->
        // sin/cos(r * 2^m) via v_sin in revolutions (cos = sin(u+0.25));
        // cm==27 -> 1.0 (bias row); cm>27 -> 0.
        half4v ov;
        #pragma unroll
        for (int j = 0; j < 4; ++j) {
            const int cm = tc * 4 + j;          // 0..31
            const int jj = cm - 3;
            const int d  = jj >> 3;
            const int mm = jj & 7;
            const float rsel = (d == 0) ? rx : ((d == 1) ? ry : rz);
            // (1<<(mm&3)) / (2*pi) via exponent add on 0x3E22F983 (=1/2pi)
            const float f2 = __int_as_float(0x3E22F983 + ((mm & 3) << 23));
            const float arg = fmaf(rsel, f2, (mm >= 4) ? 0.25f : 0.0f);
#if __has_builtin(__builtin_amdgcn_sinf)
            const float sv = __builtin_amdgcn_sinf(arg);
#else
            const float sv = __sinf(arg * 6.2831853071795864f);
#endif
            float v = (cm < 3) ? ((cm == 0) ? rx : ((cm == 1) ? ry : rz)) : sv;
            v = (cm == 27) ? 1.0f : ((cm > 27) ? 0.0f : v);
            ov[j] = (_Float16)v;
        }
        *(half4v*)&Xs[k][64 + tc * 4] = ov;
    }
    __syncthreads();

    f32x4 acc[2][4];   // lane: ch=(w*4+nt)*16+quad*4+r, pt=mt*16+l15

    // uniform (SGPR) weight bases + per-lane voffset -> saddr-form loads
    const int wu = __builtin_amdgcn_readfirstlane(w);
    const _Float16* __restrict__ w1w = w1p + (size_t)(wu * 4) * 512;
    const _Float16* __restrict__ w2w = w2p + (size_t)(wu * 4) * 512;
    const int lo8 = lane * 8;

    // ---- GEMM1: W1^T as A, X as B  ->  acc (b1 via folded row) ----
    #pragma unroll
    for (int mt = 0; mt < 2; ++mt)
        #pragma unroll
        for (int nt = 0; nt < 4; ++nt)
            acc[mt][nt] = (f32x4){0.f, 0.f, 0.f, 0.f};

    #pragma unroll
    for (int kt = 0; kt < 3; ++kt) {
        const half8 x0 = *(const half8*)&Xs[l15][kt * 32 + quad * 8];
        const half8 x1 = *(const half8*)&Xs[16 + l15][kt * 32 + quad * 8];
        #pragma unroll
        for (int nt = 0; nt < 4; ++nt) {
            const half8 wf = *(const half8*)(w1w + (kt * 16 + nt) * 512 + lo8);
            acc[0][nt] = __builtin_amdgcn_mfma_f32_16x16x32_f16(wf, x0, acc[0][nt], 0, 0, 0);
            acc[1][nt] = __builtin_amdgcn_mfma_f32_16x16x32_f16(wf, x1, acc[1][nt], 0, 0, 0);
        }
    }
    __syncthreads();   // overlay fence: all Xs reads done before H16 stores

    // ---- C-store GEMM1: raw f16, 8 contiguous ds_write_b64 (acc dies here) ----
    #pragma unroll
    for (int nt = 0; nt < 4; ++nt) {
        const int chb = (w * 4 + nt) * 16 + quad * 4;
        #pragma unroll
        for (int mt = 0; mt < 2; ++mt) {
            half4v h;
            #pragma unroll
            for (int r = 0; r < 4; ++r)
                h[r] = (_Float16)acc[mt][nt][r];
            *(half4v*)&H16[mt * 16 + l15][chb] = h;
        }
    }
    __syncthreads();

    const int row = t >> 3;         // LN ownership: thread = (row, octet p)
    const int p   = t & 7;          // owns cols [16p,16p+16) and [128+16p,+16)
    _Float16* hrow0 = &H16[row][16 * p];
    _Float16* hrow1 = &H16[row][128 + 16 * p];
    half2t ones;
    ones[0] = (_Float16)1.0f;
    ones[1] = (_Float16)1.0f;

    // ---- Phase 3: LN1 + GeLU, in place on H16 (round-8 scheme) ----
    {
        H8u u0, u1, u2, u3;
        u0.v = *(const half8*)hrow0;
        u1.v = *(const half8*)(hrow0 + 8);
        u2.v = *(const half8*)hrow1;
        u3.v = *(const half8*)(hrow1 + 8);

        float s = 0.0f, s2 = 0.0f;
        stat8(u0, ones, s, s2); stat8(u1, ones, s, s2);
        stat8(u2, ones, s, s2); stat8(u3, ones, s, s2);
        #pragma unroll
        for (int off = 1; off < 8; off <<= 1) {
            s  += __shfl_xor(s, off, 64);
            s2 += __shfl_xor(s2, off, 64);
        }
        const float mu  = s * (1.0f / 256.0f);
        const float var = fmaf(s2, 1.0f / 256.0f, -mu * mu);
        const float rs  = __builtin_amdgcn_rsqf(var + 1e-5f);
        half2t rsh, nmuh;
        rsh[0]  = (_Float16)rs;    rsh[1]  = (_Float16)rs;
        nmuh[0] = (_Float16)(-mu); nmuh[1] = (_Float16)(-mu);

        H8u gA0, gA1, gB0, gB1, bA0, bA1, bB0, bB1;
        gA0.v = *(const half8*)&g1h[16 * p];        bA0.v = *(const half8*)&be1h[16 * p];
        gA1.v = *(const half8*)&g1h[16 * p + 8];    bA1.v = *(const half8*)&be1h[16 * p + 8];
        gB0.v = *(const half8*)&g1h[128 + 16 * p];  bB0.v = *(const half8*)&be1h[128 + 16 * p];
        gB1.v = *(const half8*)&g1h[136 + 16 * p];  bB1.v = *(const half8*)&be1h[136 + 16 * p];

        norm_gelu8(u0, gA0, bA0, rsh, nmuh);
        norm_gelu8(u1, gA1, bA1, rsh, nmuh);
        norm_gelu8(u2, gB0, bB0, rsh, nmuh);
        norm_gelu8(u3, gB1, bB1, rsh, nmuh);

        *(half8*)hrow0       = u0.v;
        *(half8*)(hrow0 + 8) = u1.v;
        *(half8*)hrow1       = u2.v;
        *(half8*)(hrow1 + 8) = u3.v;
    }
    __syncthreads();

    // ---- GEMM2: W2^T as A, H as B ----
    #pragma unroll
    for (int mt = 0; mt < 2; ++mt)
        #pragma unroll
        for (int nt = 0; nt < 4; ++nt)
            acc[mt][nt] = (f32x4){0.f, 0.f, 0.f, 0.f};

    #pragma unroll
    for (int kt = 0; kt < 8; ++kt) {
        const half8 h0 = *(const half8*)&H16[l15][kt * 32 + quad * 8];
        const half8 h1 = *(const half8*)&H16[16 + l15][kt * 32 + quad * 8];
        #pragma unroll
        for (int nt = 0; nt < 4; ++nt) {
            const half8 wf = *(const half8*)(w2w + (kt * 16 + nt) * 512 + lo8);
            acc[0][nt] = __builtin_amdgcn_mfma_f32_16x16x32_f16(wf, h0, acc[0][nt], 0, 0, 0);
            acc[1][nt] = __builtin_amdgcn_mfma_f32_16x16x32_f16(wf, h1, acc[1][nt], 0, 0, 0);
        }
    }
    __syncthreads();   // ALL B-reads of H16 done before in-place C-store

    // ---- C-store GEMM2: +b2, raw f16, contiguous b64 (acc dies here) ----
    #pragma unroll
    for (int nt = 0; nt < 4; ++nt) {
        const int chb = (w * 4 + nt) * 16 + quad * 4;
        const f32x4 bv = *(const f32x4*)&b2[chb];
        #pragma unroll
        for (int mt = 0; mt < 2; ++mt) {
            half4v h;
            #pragma unroll
            for (int r = 0; r < 4; ++r)
                h[r] = (_Float16)(acc[mt][nt][r] + bv[r]);
            *(half4v*)&H16[mt * 16 + l15][chb] = h;
        }
    }
    __syncthreads();

    // ---- Phase 5: LN2 (no activation), in place on H16 ----
    {
        H8u u0, u1, u2, u3;
        u0.v = *(const half8*)hrow0;
        u1.v = *(const half8*)(hrow0 + 8);
        u2.v = *(const half8*)hrow1;
        u3.v = *(const half8*)(hrow1 + 8);

        float s = 0.0f, s2 = 0.0f;
        stat8(u0, ones, s, s2); stat8(u1, ones, s, s2);
        stat8(u2, ones, s, s2); stat8(u3, ones, s, s2);
        #pragma unroll
        for (int off = 1; off < 8; off <<= 1) {
            s  += __shfl_xor(s, off, 64);
            s2 += __shfl_xor(s2, off, 64);
        }
        const float mu  = s * (1.0f / 256.0f);
        const float var = fmaf(s2, 1.0f / 256.0f, -mu * mu);
        const float rs  = __builtin_amdgcn_rsqf(var + 1e-5f);
        half2t rsh, nmuh;
        rsh[0]  = (_Float16)rs;    rsh[1]  = (_Float16)rs;
        nmuh[0] = (_Float16)(-mu); nmuh[1] = (_Float16)(-mu);

        H8u gA0, gA1, gB0, gB1, bA0, bA1, bB0, bB1;
        gA0.v = *(const half8*)&g2h[16 * p];        bA0.v = *(const half8*)&be2h[16 * p];
        gA1.v = *(const half8*)&g2h[16 * p + 8];    bA1.v = *(const half8*)&be2h[16 * p + 8];
        gB0.v = *(const half8*)&g2h[128 + 16 * p];  bB0.v = *(const half8*)&be2h[128 + 16 * p];
        gB1.v = *(const half8*)&g2h[136 + 16 * p];  bB1.v = *(const half8*)&be2h[136 + 16 * p];

        norm8(u0, gA0, bA0, rsh, nmuh);
        norm8(u1, gA1, bA1, rsh, nmuh);
        norm8(u2, gB0, bB0, rsh, nmuh);
        norm8(u3, gB1, bB1, rsh, nmuh);

        *(half8*)hrow0       = u0.v;
        *(half8*)(hrow0 + 8) = u1.v;
        *(half8*)hrow1       = u2.v;
        *(half8*)(hrow1 + 8) = u3.v;
    }
    __syncthreads();

    // ---- Phase 6: packed max over 32 points, coalesced float2 store ----
    if (t < 128) {
        const _Float16* Hf = &H16[0][0];
        half2t mx = *(const half2t*)(Hf + 2 * t);
        #pragma unroll
        for (int r = 1; r < KN; ++r) {
            const half2t v = *(const half2t*)(Hf + r * HSTR + 2 * t);
            mx = __builtin_elementwise_max(mx, v);
        }
        float2 o2;
        o2.x = (float)mx[0];
        o2.y = (float)mx[1];
        *(float2*)&out0[(size_t)q * C + 2 * t] = o2;
    }
}

extern "C" void kernel_launch(void* const* d_in, const int* in_sizes, int n_in,
                              void* d_out, int out_size, void* d_ws, size_t ws_size,
                              hipStream_t stream) {
    const float* xyz = (const float*)d_in[0];
    const float* pf  = (const float*)d_in[1];
    const float* ctr = (const float*)d_in[2];
    const float* W1  = (const float*)d_in[3];
    const float* b1  = (const float*)d_in[4];
    const float* g1  = (const float*)d_in[5];
    const float* be1 = (const float*)d_in[6];
    const float* W2  = (const float*)d_in[7];
    const float* b2  = (const float*)d_in[8];
    const float* g2  = (const float*)d_in[9];
    const float* be2 = (const float*)d_in[10];

    float* out = (float*)d_out;
    _Float16* wp = (_Float16*)d_ws;
    float4* xyzw = (float4*)(wp + WP_ELEMS);   // 180224 B offset, 16-aligned; +2 MB

    prep_kernel<<<(WP_ELEMS + NPTS * 8) / 256, 256, 0, stream>>>(W1, b1, W2, xyz, wp, xyzw);
    encoder_fused<<<NQ, 256, 0, stream>>>(xyzw, pf, ctr,
                                          g1, be1, b2, g2, be2,
                                          wp, wp + W1P_ELEMS,
                                          out, out + PF_ELEMS);
}

// Round 3
// 186.726 us; speedup vs baseline: 1.0089x; 1.0089x over previous
//
#include <hip/hip_runtime.h>
#include <math.h>

#define NPTS 16384
#define NPTS_PAD 16896       // +512 float4 pad per batch for scan prefetch
#define KN 32
#define C 256
#define NQ 8192              // 8 * 1024 queries
#define PF_ELEMS (NQ * C)

#define W1P_ELEMS (3 * 16 * 64 * 8)                 // 24576  (Ktiles=3, Ntiles=16)
#define W2P_ELEMS (8 * 16 * 64 * 8)                 // 65536  (Ktiles=8)
#define WP_ELEMS  (W1P_ELEMS + W2P_ELEMS)           // 90112 halves = 180224 B (16-aligned)
#define XYZW_ELEMS (8 * NPTS_PAD)                   // 135168 float4
#define HSTR 264                                    // halves per H16 row

typedef _Float16 half8 __attribute__((ext_vector_type(8)));
typedef _Float16 half4v __attribute__((ext_vector_type(4)));
typedef _Float16 half2t __attribute__((ext_vector_type(2)));
typedef float f32x4 __attribute__((ext_vector_type(4)));

// tanh-approx GeLU: max err ~3e-4.  y = x - x/(e^{2u}+1)
__device__ __forceinline__ float gelu_tanh(float x) {
    const float t  = x * x;
    const float p2 = fmaf(t, 0.0713548162726f, 1.59576912161f);
    const float e  = __expf(x * p2);
    return x - x * __builtin_amdgcn_rcpf(e + 1.0f);
}

// ---------------------------------------------------------------------------
// Prep: pack W1 (91x256 + b1 folded at k=91, K-padded to 96) and W2 (256x256)
// into f16 fragment order; pack xyz into float4 (x,y,z,|p|^2) with the EXACT
// rounding sequence the encoder's ball query uses (bit-identical membership).
// xyzw is padded per batch to NPTS_PAD (scan prefetch overruns by <=512).
//   flat = ((kt*16 + nt)*64 + lane)*8 + j
//   k = kt*32 + (lane>>4)*8 + j ;  ch = nt*16 + (lane&15)
// ---------------------------------------------------------------------------
__global__ void prep_kernel(const float* __restrict__ W1,
                            const float* __restrict__ b1,
                            const float* __restrict__ W2,
                            const float* __restrict__ xyz,
                            _Float16* __restrict__ wp,
                            float4* __restrict__ xyzw) {
    const int idx = blockIdx.x * 256 + threadIdx.x;   // 0 .. 225279
    if (idx < 96 * 256) {
        const int k = idx >> 8, n = idx & 255;
        const float v = (k < 91) ? W1[k * 256 + n] : ((k == 91) ? b1[n] : 0.0f);
        const int kt = k >> 5, quad = (k >> 3) & 3, j = k & 7;
        const int nt = n >> 4, l15 = n & 15;
        wp[(((kt * 16 + nt) * 64) + quad * 16 + l15) * 8 + j] = (_Float16)v;
    } else if (idx < WP_ELEMS) {
        const int e = idx - 96 * 256;
        const int k = e >> 8, n = e & 255;
        const int kt = k >> 5, quad = (k >> 3) & 3, j = k & 7;
        const int nt = n >> 4, l15 = n & 15;
        wp[W1P_ELEMS + (((kt * 16 + nt) * 64) + quad * 16 + l15) * 8 + j] =
            (_Float16)W2[k * 256 + n];
    } else {
        const int e  = idx - WP_ELEMS;                // 0 .. 135167
        const int bb = e / NPTS_PAD;
        const int off = e - bb * NPTS_PAD;
        float4 v;
        if (off < NPTS) {
            const float px = xyz[((size_t)bb * NPTS + off) * 3 + 0];
            const float py = xyz[((size_t)bb * NPTS + off) * 3 + 1];
            const float pz = xyz[((size_t)bb * NPTS + off) * 3 + 2];
            const float sp = __fadd_rn(__fadd_rn(__fmul_rn(px, px), __fmul_rn(py, py)),
                                       __fmul_rn(pz, pz));
            v = make_float4(px, py, pz, sp);
        } else {
            v = make_float4(1e9f, 1e9f, 1e9f, 3e18f);  // sentinel pad (never in-ball)
        }
        xyzw[(size_t)bb * NPTS_PAD + off] = v;
    }
}

// ---------------------------------------------------------------------------
// Fused: ball-query + gather/posenc + MLP1(LN,GeLU) + MLP2(LN) + max.
// Round-16 (session R3): barrier/latency round on the R2 structure.
//  * ball query: 512 pts/iter (2-group ordered compaction, exact first-32
//    semantics) + software prefetch of next iter's float4s (xyzw padded) ->
//    halves scan barriers and hides per-iter L2 latency.
//  * LN1+GeLU fused into GEMM1 epilogue, LN2 into GEMM2 epilogue: stats on
//    f32 accs in-register (quad shfl_xor + 1KB sred cross-warp partials),
//    normalize+activate in f32, single f16 store. Kills both LDS rmw passes,
//    2 barriers, ~64 cvts/wave; stats numerics closer to reference.
//  * keeps R1/R2: saddr weight loads, packed (x,y,z,|p|^2), branchless
//    revolution-domain posenc, Xs/H16 overlay, __launch_bounds__(256,8).
// LDS 20160 -> 20480 block (8 x 20480 = 163840 = exactly 160 KiB).
// No runtime-indexed private arrays (round-3 lesson).
// ---------------------------------------------------------------------------
__global__ void __launch_bounds__(256, 8)
encoder_fused(const float4* __restrict__ xyzw,
              const float* __restrict__ pf,
              const float* __restrict__ ctr,
              const float* __restrict__ g1, const float* __restrict__ be1,
              const float* __restrict__ b2, const float* __restrict__ g2,
              const float* __restrict__ be2,
              const _Float16* __restrict__ w1p,
              const _Float16* __restrict__ w2p,
              float* __restrict__ out0,      // patch_feature [8192][256]
              float* __restrict__ out1) {    // neighbor idx as float [8192][32]
    const int q = blockIdx.x;
    const int b = q >> 10;
    const int t = threadIdx.x;
    const int w = t >> 6;
    const int lane = t & 63;
    const int quad = lane >> 4;
    const int l15  = lane & 15;

    // Overlaid region: Xs f16[32][104] (phase1 -> GEMM1) then H16 f16[32][264]
    // (LN1 store -> phase 6). Transition fenced by the stats barrier.
    __shared__ __align__(16) unsigned char H16raw[KN * HSTR * 2];  // 16896
    __shared__ __align__(16) _Float16 lnph[4 * 256];               // 2048: g1,be1,g2,be2
    __shared__ __align__(16) float2 sred[2][16][4];                // 1024: [mt][l15][w]
    __shared__ int nbr[KN];
    __shared__ int wcnt[2][2][4];                                  // [par][grp][warp]

    _Float16 (*H16)[HSTR] = (_Float16(*)[HSTR])H16raw;
    _Float16 (*Xs)[104]   = (_Float16(*)[104])H16raw;   // OVERLAY
    _Float16* g1h  = lnph;
    _Float16* be1h = lnph + 256;
    _Float16* g2h  = lnph + 512;
    _Float16* be2h = lnph + 768;

    lnph[t]       = (_Float16)g1[t];
    lnph[256 + t] = (_Float16)be1[t];
    lnph[512 + t] = (_Float16)g2[t];
    lnph[768 + t] = (_Float16)be2[t];

    // ---- Phase 0: ball query, 512 pts/iter, prefetched ----
    // first-32-ascending == reference sort+slice; exact unfused fp32 formula
    // (|p|^2 precomputed in prep with the same rounding -> identical bits).
    const float4* xwb = xyzw + (size_t)b * NPTS_PAD;
    const float cx = ctr[q * 3 + 0];
    const float cy = ctr[q * 3 + 1];
    const float cz = ctr[q * 3 + 2];
    const float sc = __fadd_rn(__fadd_rn(__fmul_rn(cx, cx), __fmul_rn(cy, cy)),
                               __fmul_rn(cz, cz));

    float4 pw0 = xwb[t];
    float4 pw1 = xwb[256 + t];
    int found = 0;
    int par = 0;
    for (int base = 0; base < NPTS; base += 512) {
        // prefetch next iteration (pad guarantees in-bounds; values unused at tail)
        const float4 nx0 = xwb[base + 512 + t];
        const float4 nx1 = xwb[base + 768 + t];

        const float dt0 = __fadd_rn(__fadd_rn(__fmul_rn(cx, pw0.x), __fmul_rn(cy, pw0.y)),
                                    __fmul_rn(cz, pw0.z));
        const float sq0 = __fsub_rn(__fadd_rn(sc, pw0.w), __fmul_rn(2.0f, dt0));
        const float dt1 = __fadd_rn(__fadd_rn(__fmul_rn(cx, pw1.x), __fmul_rn(cy, pw1.y)),
                                    __fmul_rn(cz, pw1.z));
        const float sq1 = __fsub_rn(__fadd_rn(sc, pw1.w), __fmul_rn(2.0f, dt1));
        const bool in0 = (sq0 <= 0.0625f);
        const bool in1 = (sq1 <= 0.0625f);

        const unsigned long long m0 = __ballot(in0);
        const unsigned long long m1 = __ballot(in1);
        if (lane == 0) {
            wcnt[par][0][w] = (int)__popcll(m0);
            wcnt[par][1][w] = (int)__popcll(m1);
        }
        __syncthreads();
        const int c00 = wcnt[par][0][0], c01 = wcnt[par][0][1];
        const int c02 = wcnt[par][0][2], c03 = wcnt[par][0][3];
        const int c10 = wcnt[par][1][0], c11 = wcnt[par][1][1];
        const int c12 = wcnt[par][1][2], c13 = wcnt[par][1][3];
        int pre0 = found;
        if (w > 0) pre0 += c00;
        if (w > 1) pre0 += c01;
        if (w > 2) pre0 += c02;
        const int C0 = c00 + c01 + c02 + c03;
        int pre1 = found + C0;
        if (w > 0) pre1 += c10;
        if (w > 1) pre1 += c11;
        if (w > 2) pre1 += c12;
        const int tot = C0 + c10 + c11 + c12 + c13;
        const unsigned long long lmask = (1ull << lane) - 1ull;
        const int pos0 = pre0 + (int)__popcll(m0 & lmask);
        const int pos1 = pre1 + (int)__popcll(m1 & lmask);
        if (in0 && pos0 < KN) nbr[pos0] = base + t;
        if (in1 && pos1 < KN) nbr[pos1] = base + 256 + t;
        found += tot;                 // block-uniform
        par ^= 1;
        if (found >= KN) break;
        pw0 = nx0;
        pw1 = nx1;
    }
    __syncthreads();                  // nbr visible to all
    const int count = (found < KN) ? found : KN;
    const int first = (count > 0) ? nbr[0] : NPTS;

    if (t < KN)
        out1[(size_t)q * KN + t] = (float)((t < count) ? nbr[t] : first);

    // ---- Phase 1: gather + rel + posenc into Xs (f16; k=91 is 1.0 for b1) ----
    {
        const int k  = t >> 3;
        const int tc = t & 7;
        const int nidx = (k < count) ? nbr[k] : first;
        const int n = (nidx < NPTS) ? nidx : NPTS - 1;   // JAX OOB gather clamp
        const float4 pw = xwb[n];
        const float rx = pw.x - cx;
        const float ry = pw.y - cy;
        const float rz = pw.z - cz;
        const float* pfr = pf + ((size_t)b * NPTS + n) * 64;

        const float4 f0 = *(const float4*)(pfr + tc * 8);
        const float4 f1 = *(const float4*)(pfr + tc * 8 + 4);
        half8 hv;
        hv[0] = (_Float16)f0.x; hv[1] = (_Float16)f0.y;
        hv[2] = (_Float16)f0.z; hv[3] = (_Float16)f0.w;
        hv[4] = (_Float16)f1.x; hv[5] = (_Float16)f1.y;
        hv[6] = (_Float16)f1.z; hv[7] = (_Float16)f1.w;
        *(half8*)&Xs[k][tc * 8] = hv;

        // branchless posenc: ch c = 64+cm; cm<3 -> raw rel; 3<=cm<27 ->
        // sin/cos(r * 2^m) via v_sin in revolutions (cos = sin(u+0.25));
        // cm==27 -> 1.0 (bias row); cm>27 -> 0.
        half4v ov;
        #pragma unroll
        for (int j = 0; j < 4; ++j) {
            const int cm = tc * 4 + j;          // 0..31
            const int jj = cm - 3;
            const int d  = jj >> 3;
            const int mm = jj & 7;
            const float rsel = (d == 0) ? rx : ((d == 1) ? ry : rz);
            // (1<<(mm&3)) / (2*pi) via exponent add on 0x3E22F983 (=1/2pi)
            const float f2 = __int_as_float(0x3E22F983 + ((mm & 3) << 23));
            const float arg = fmaf(rsel, f2, (mm >= 4) ? 0.25f : 0.0f);
#if __has_builtin(__builtin_amdgcn_sinf)
            const float sv = __builtin_amdgcn_sinf(arg);
#else
            const float sv = __sinf(arg * 6.2831853071795864f);
#endif
            float v = (cm < 3) ? ((cm == 0) ? rx : ((cm == 1) ? ry : rz)) : sv;
            v = (cm == 27) ? 1.0f : ((cm > 27) ? 0.0f : v);
            ov[j] = (_Float16)v;
        }
        *(half4v*)&Xs[k][64 + tc * 4] = ov;
    }
    __syncthreads();

    f32x4 acc[2][4];   // lane: ch=(w*4+nt)*16+quad*4+r, pt=mt*16+l15

    // uniform (SGPR) weight bases + per-lane voffset -> saddr-form loads
    const int wu = __builtin_amdgcn_readfirstlane(w);
    const _Float16* __restrict__ w1w = w1p + (size_t)(wu * 4) * 512;
    const _Float16* __restrict__ w2w = w2p + (size_t)(wu * 4) * 512;
    const int lo8 = lane * 8;

    // ---- GEMM1: W1^T as A, X as B  ->  acc (b1 via folded row) ----
    #pragma unroll
    for (int mt = 0; mt < 2; ++mt)
        #pragma unroll
        for (int nt = 0; nt < 4; ++nt)
            acc[mt][nt] = (f32x4){0.f, 0.f, 0.f, 0.f};

    #pragma unroll
    for (int kt = 0; kt < 3; ++kt) {
        const half8 x0 = *(const half8*)&Xs[l15][kt * 32 + quad * 8];
        const half8 x1 = *(const half8*)&Xs[16 + l15][kt * 32 + quad * 8];
        #pragma unroll
        for (int nt = 0; nt < 4; ++nt) {
            const half8 wf = *(const half8*)(w1w + (kt * 16 + nt) * 512 + lo8);
            acc[0][nt] = __builtin_amdgcn_mfma_f32_16x16x32_f16(wf, x0, acc[0][nt], 0, 0, 0);
            acc[1][nt] = __builtin_amdgcn_mfma_f32_16x16x32_f16(wf, x1, acc[1][nt], 0, 0, 0);
        }
    }

    // ---- LN1 stats on f32 accs (in-register + quad shfl + cross-warp LDS) ----
    float mu0, mu1, rs0, rs1;
    {
        #pragma unroll
        for (int mt = 0; mt < 2; ++mt) {
            float s = 0.0f, s2 = 0.0f;
            #pragma unroll
            for (int nt = 0; nt < 4; ++nt)
                #pragma unroll
                for (int r = 0; r < 4; ++r) {
                    const float v = acc[mt][nt][r];
                    s += v;
                    s2 = fmaf(v, v, s2);
                }
            s  += __shfl_xor(s, 16, 64);  s  += __shfl_xor(s, 32, 64);
            s2 += __shfl_xor(s2, 16, 64); s2 += __shfl_xor(s2, 32, 64);
            if (quad == 0) sred[mt][l15][w] = make_float2(s, s2);
        }
    }
    __syncthreads();   // overlay fence (Xs reads done) + sred partials visible
    {
        #pragma unroll
        for (int mt = 0; mt < 2; ++mt) {
            const float4 pA = *(const float4*)&sred[mt][l15][0];
            const float4 pB = *(const float4*)&sred[mt][l15][2];
            const float S = pA.x + pA.z + pB.x + pB.z;
            const float Q = pA.y + pA.w + pB.y + pB.w;
            const float mu = S * (1.0f / 256.0f);
            const float var = fmaf(Q, 1.0f / 256.0f, -mu * mu);
            const float rs = __builtin_amdgcn_rsqf(var + 1e-5f);
            if (mt == 0) { mu0 = mu; rs0 = rs; } else { mu1 = mu; rs1 = rs; }
        }
    }

    // ---- LN1 apply + GeLU in f32, single f16 store into H16 ----
    #pragma unroll
    for (int nt = 0; nt < 4; ++nt) {
        const int chb = (w * 4 + nt) * 16 + quad * 4;
        const half4v g4h  = *(const half4v*)&g1h[chb];
        const half4v be4h = *(const half4v*)&be1h[chb];
        #pragma unroll
        for (int mt = 0; mt < 2; ++mt) {
            const float mu = (mt == 0) ? mu0 : mu1;
            const float rs = (mt == 0) ? rs0 : rs1;
            half4v h;
            #pragma unroll
            for (int r = 0; r < 4; ++r) {
                const float A = (float)g4h[r] * rs;
                const float y = fmaf(acc[mt][nt][r] - mu, A, (float)be4h[r]);
                h[r] = (_Float16)gelu_tanh(y);
            }
            *(half4v*)&H16[mt * 16 + l15][chb] = h;
        }
    }
    __syncthreads();   // H16 ready for GEMM2 B-reads

    // ---- GEMM2: W2^T as A, H as B ----
    #pragma unroll
    for (int mt = 0; mt < 2; ++mt)
        #pragma unroll
        for (int nt = 0; nt < 4; ++nt)
            acc[mt][nt] = (f32x4){0.f, 0.f, 0.f, 0.f};

    #pragma unroll
    for (int kt = 0; kt < 8; ++kt) {
        const half8 h0 = *(const half8*)&H16[l15][kt * 32 + quad * 8];
        const half8 h1 = *(const half8*)&H16[16 + l15][kt * 32 + quad * 8];
        #pragma unroll
        for (int nt = 0; nt < 4; ++nt) {
            const half8 wf = *(const half8*)(w2w + (kt * 16 + nt) * 512 + lo8);
            acc[0][nt] = __builtin_amdgcn_mfma_f32_16x16x32_f16(wf, h0, acc[0][nt], 0, 0, 0);
            acc[1][nt] = __builtin_amdgcn_mfma_f32_16x16x32_f16(wf, h1, acc[1][nt], 0, 0, 0);
        }
    }

    // ---- +b2, LN2 stats on f32 accs ----
    #pragma unroll
    for (int nt = 0; nt < 4; ++nt) {
        const f32x4 bv = *(const f32x4*)&b2[(w * 4 + nt) * 16 + quad * 4];
        #pragma unroll
        for (int mt = 0; mt < 2; ++mt)
            #pragma unroll
            for (int r = 0; r < 4; ++r)
                acc[mt][nt][r] += bv[r];
    }
    {
        #pragma unroll
        for (int mt = 0; mt < 2; ++mt) {
            float s = 0.0f, s2 = 0.0f;
            #pragma unroll
            for (int nt = 0; nt < 4; ++nt)
                #pragma unroll
                for (int r = 0; r < 4; ++r) {
                    const float v = acc[mt][nt][r];
                    s += v;
                    s2 = fmaf(v, v, s2);
                }
            s  += __shfl_xor(s, 16, 64);  s  += __shfl_xor(s, 32, 64);
            s2 += __shfl_xor(s2, 16, 64); s2 += __shfl_xor(s2, 32, 64);
            if (quad == 0) sred[mt][l15][w] = make_float2(s, s2);
        }
    }
    __syncthreads();   // ALL H16 B-reads done (in-place store safe) + partials
    {
        #pragma unroll
        for (int mt = 0; mt < 2; ++mt) {
            const float4 pA = *(const float4*)&sred[mt][l15][0];
            const float4 pB = *(const float4*)&sred[mt][l15][2];
            const float S = pA.x + pA.z + pB.x + pB.z;
            const float Q = pA.y + pA.w + pB.y + pB.w;
            const float mu = S * (1.0f / 256.0f);
            const float var = fmaf(Q, 1.0f / 256.0f, -mu * mu);
            const float rs = __builtin_amdgcn_rsqf(var + 1e-5f);
            if (mt == 0) { mu0 = mu; rs0 = rs; } else { mu1 = mu; rs1 = rs; }
        }
    }

    // ---- LN2 apply (no activation), f16 store into H16 ----
    #pragma unroll
    for (int nt = 0; nt < 4; ++nt) {
        const int chb = (w * 4 + nt) * 16 + quad * 4;
        const half4v g4h  = *(const half4v*)&g2h[chb];
        const half4v be4h = *(const half4v*)&be2h[chb];
        #pragma unroll
        for (int mt = 0; mt < 2; ++mt) {
            const float mu = (mt == 0) ? mu0 : mu1;
            const float rs = (mt == 0) ? rs0 : rs1;
            half4v h;
            #pragma unroll
            for (int r = 0; r < 4; ++r) {
                const float A = (float)g4h[r] * rs;
                h[r] = (_Float16)fmaf(acc[mt][nt][r] - mu, A, (float)be4h[r]);
            }
            *(half4v*)&H16[mt * 16 + l15][chb] = h;
        }
    }
    __syncthreads();

    // ---- Phase 6: packed max over 32 points, coalesced float2 store ----
    if (t < 128) {
        const _Float16* Hf = &H16[0][0];
        half2t mx = *(const half2t*)(Hf + 2 * t);
        #pragma unroll
        for (int r = 1; r < KN; ++r) {
            const half2t v = *(const half2t*)(Hf + r * HSTR + 2 * t);
            mx = __builtin_elementwise_max(mx, v);
        }
        float2 o2;
        o2.x = (float)mx[0];
        o2.y = (float)mx[1];
        *(float2*)&out0[(size_t)q * C + 2 * t] = o2;
    }
}

extern "C" void kernel_launch(void* const* d_in, const int* in_sizes, int n_in,
                              void* d_out, int out_size, void* d_ws, size_t ws_size,
                              hipStream_t stream) {
    const float* xyz = (const float*)d_in[0];
    const float* pf  = (const float*)d_in[1];
    const float* ctr = (const float*)d_in[2];
    const float* W1  = (const float*)d_in[3];
    const float* b1  = (const float*)d_in[4];
    const float* g1  = (const float*)d_in[5];
    const float* be1 = (const float*)d_in[6];
    const float* W2  = (const float*)d_in[7];
    const float* b2  = (const float*)d_in[8];
    const float* g2  = (const float*)d_in[9];
    const float* be2 = (const float*)d_in[10];

    float* out = (float*)d_out;
    _Float16* wp = (_Float16*)d_ws;
    float4* xyzw = (float4*)(wp + WP_ELEMS);   // 180224 B offset, 16-aligned; +2.06 MB

    prep_kernel<<<(WP_ELEMS + XYZW_ELEMS) / 256, 256, 0, stream>>>(W1, b1, W2, xyz, wp, xyzw);
    encoder_fused<<<NQ, 256, 0, stream>>>(xyzw, pf, ctr,
                                          g1, be1, b2, g2, be2,
                                          wp, wp + W1P_ELEMS,
                                          out, out + PF_ELEMS);
}

// Round 4
// 180.088 us; speedup vs baseline: 1.0461x; 1.0369x over previous
//
#include <hip/hip_runtime.h>
#include <math.h>

#define NPTS 16384
#define NPTS_PAD 16896       // +512 float4 pad per batch for scan prefetch
#define KN 32
#define C 256
#define NQ 8192              // 8 * 1024 queries
#define PF_ELEMS (NQ * C)

#define W1P_ELEMS (3 * 16 * 64 * 8)                 // 24576  (Ktiles=3, Ntiles=16)
#define W2P_ELEMS (8 * 16 * 64 * 8)                 // 65536  (Ktiles=8)
#define WP_ELEMS  (W1P_ELEMS + W2P_ELEMS)           // 90112 halves = 180224 B (16-aligned)
#define XYZW_ELEMS (8 * NPTS_PAD)                   // 135168 float4
#define HSTR 264                                    // halves per H16 row

typedef _Float16 half8 __attribute__((ext_vector_type(8)));
typedef _Float16 half4v __attribute__((ext_vector_type(4)));
typedef _Float16 half2t __attribute__((ext_vector_type(2)));
typedef float f32x4 __attribute__((ext_vector_type(4)));

// tanh-approx GeLU: max err ~3e-4.  y = x - x/(e^{2u}+1)
__device__ __forceinline__ float gelu_tanh(float x) {
    const float t  = x * x;
    const float p2 = fmaf(t, 0.0713548162726f, 1.59576912161f);
    const float e  = __expf(x * p2);
    return x - x * __builtin_amdgcn_rcpf(e + 1.0f);
}

// ---------------------------------------------------------------------------
// Prep: pack W1 (91x256 + b1 folded at k=91, K-padded to 96) and W2 (256x256)
// into f16 fragment order; pack xyz into float4 (x,y,z,|p|^2) with the EXACT
// rounding sequence the encoder's ball query uses (bit-identical membership).
// xyzw is padded per batch to NPTS_PAD (scan prefetch overruns by <=512).
//   flat = ((kt*16 + nt)*64 + lane)*8 + j
//   k = kt*32 + (lane>>4)*8 + j ;  ch = nt*16 + (lane&15)
// ---------------------------------------------------------------------------
__global__ void prep_kernel(const float* __restrict__ W1,
                            const float* __restrict__ b1,
                            const float* __restrict__ W2,
                            const float* __restrict__ xyz,
                            _Float16* __restrict__ wp,
                            float4* __restrict__ xyzw) {
    const int idx = blockIdx.x * 256 + threadIdx.x;   // 0 .. 225279
    if (idx < 96 * 256) {
        const int k = idx >> 8, n = idx & 255;
        const float v = (k < 91) ? W1[k * 256 + n] : ((k == 91) ? b1[n] : 0.0f);
        const int kt = k >> 5, quad = (k >> 3) & 3, j = k & 7;
        const int nt = n >> 4, l15 = n & 15;
        wp[(((kt * 16 + nt) * 64) + quad * 16 + l15) * 8 + j] = (_Float16)v;
    } else if (idx < WP_ELEMS) {
        const int e = idx - 96 * 256;
        const int k = e >> 8, n = e & 255;
        const int kt = k >> 5, quad = (k >> 3) & 3, j = k & 7;
        const int nt = n >> 4, l15 = n & 15;
        wp[W1P_ELEMS + (((kt * 16 + nt) * 64) + quad * 16 + l15) * 8 + j] =
            (_Float16)W2[k * 256 + n];
    } else {
        const int e  = idx - WP_ELEMS;                // 0 .. 135167
        const int bb = e / NPTS_PAD;
        const int off = e - bb * NPTS_PAD;
        float4 v;
        if (off < NPTS) {
            const float px = xyz[((size_t)bb * NPTS + off) * 3 + 0];
            const float py = xyz[((size_t)bb * NPTS + off) * 3 + 1];
            const float pz = xyz[((size_t)bb * NPTS + off) * 3 + 2];
            const float sp = __fadd_rn(__fadd_rn(__fmul_rn(px, px), __fmul_rn(py, py)),
                                       __fmul_rn(pz, pz));
            v = make_float4(px, py, pz, sp);
        } else {
            v = make_float4(1e9f, 1e9f, 1e9f, 3e18f);  // sentinel pad (never in-ball)
        }
        xyzw[(size_t)bb * NPTS_PAD + off] = v;
    }
}

// ---------------------------------------------------------------------------
// Fused: ball-query + gather/posenc + MLP1(LN,GeLU) + MLP2(LN) + max.
// Round-17 (session R4): TWO QUERIES PER BLOCK.
//  * R3 post-mortem: barrier/LN-pass removal was flat -> binding resource is
//    per-CU L2 weight bandwidth (176KB W1+W2 re-read per block, ~42us of the
//    104us wall) + exposed VMEM latency in the GEMM loops.
//  * Block handles queries 2i,2i+1 (same batch): each weight fragment feeds
//    4 MFMAs (was 2) -> weight L2 traffic + weight-load count HALVE per
//    query; one xyzw scan serves both centers (scan loads + barriers ~halve
//    per query); MFMA:VMEM ratio doubles.
//  * Phase-6 max now uses all 256 threads (t>>7 selects query).
//  * acc[2][2][4] = 64 VGPRs; __launch_bounds__(256,4); LDS ~38.3KB ->
//    4 blocks/CU = 8 in-flight queries/CU (same as R3's 8).
//  * keeps R1-R3: saddr weight loads, packed (x,y,z,|p|^2), branchless
//    revolution-domain posenc, Xs/H16 overlay, fused LN epilogues (f32
//    stats in-register + sred cross-warp partials).
// No runtime-indexed private arrays (all multi-dim arrays under #pragma
// unroll with compile-time indices).
// ---------------------------------------------------------------------------
__global__ void __launch_bounds__(256, 4)
encoder_fused(const float4* __restrict__ xyzw,
              const float* __restrict__ pf,
              const float* __restrict__ ctr,
              const float* __restrict__ g1, const float* __restrict__ be1,
              const float* __restrict__ b2, const float* __restrict__ g2,
              const float* __restrict__ be2,
              const _Float16* __restrict__ w1p,
              const _Float16* __restrict__ w2p,
              float* __restrict__ out0,      // patch_feature [8192][256]
              float* __restrict__ out1) {    // neighbor idx as float [8192][32]
    const int q0 = blockIdx.x * 2;           // queries q0, q0+1 (same batch b)
    const int b = q0 >> 10;
    const int t = threadIdx.x;
    const int w = t >> 6;
    const int lane = t & 63;
    const int quad = lane >> 4;
    const int l15  = lane & 15;

    // Overlaid regions: XsQ f16[32][104] (phase1 -> GEMM1) then H16Q
    // f16[32][264] (LN1 store -> phase 6), per query. Fenced by stats barrier.
    __shared__ __align__(16) unsigned char H16raw[2][KN * HSTR * 2];  // 33792
    __shared__ __align__(16) _Float16 lnph[4 * 256];                  // 2048
    __shared__ __align__(16) float2 sred[2][2][16][4];                // 2048: [qq][mt][l15][w]
    __shared__ int nbr[2][KN];                                        // 256
    __shared__ int wcnt[2][2][2][4];                                  // [par][qq][grp][warp]

    _Float16 (*H16a)[HSTR] = (_Float16(*)[HSTR])H16raw[0];
    _Float16 (*H16b)[HSTR] = (_Float16(*)[HSTR])H16raw[1];
    _Float16 (*Xs0)[104]   = (_Float16(*)[104])H16raw[0];   // OVERLAY
    _Float16 (*Xs1)[104]   = (_Float16(*)[104])H16raw[1];   // OVERLAY
    _Float16* g1h  = lnph;
    _Float16* be1h = lnph + 256;
    _Float16* g2h  = lnph + 512;
    _Float16* be2h = lnph + 768;

    lnph[t]       = (_Float16)g1[t];
    lnph[256 + t] = (_Float16)be1[t];
    lnph[512 + t] = (_Float16)g2[t];
    lnph[768 + t] = (_Float16)be2[t];

    // ---- Phase 0: shared ball query for both centers, 512 pts/iter ----
    // first-32-ascending == reference sort+slice; exact unfused fp32 formula
    // (|p|^2 precomputed in prep with the same rounding -> identical bits).
    const float4* xwb = xyzw + (size_t)b * NPTS_PAD;
    const float cxA = ctr[q0 * 3 + 0], cyA = ctr[q0 * 3 + 1], czA = ctr[q0 * 3 + 2];
    const float cxB = ctr[q0 * 3 + 3], cyB = ctr[q0 * 3 + 4], czB = ctr[q0 * 3 + 5];
    const float scA = __fadd_rn(__fadd_rn(__fmul_rn(cxA, cxA), __fmul_rn(cyA, cyA)),
                                __fmul_rn(czA, czA));
    const float scB = __fadd_rn(__fadd_rn(__fmul_rn(cxB, cxB), __fmul_rn(cyB, cyB)),
                                __fmul_rn(czB, czB));

    float4 pw0 = xwb[t];
    float4 pw1 = xwb[256 + t];
    int foundA = 0, foundB = 0;
    int par = 0;
    for (int base = 0; base < NPTS; base += 512) {
        // prefetch next iteration (pad guarantees in-bounds; unused at tail)
        const float4 nx0 = xwb[base + 512 + t];
        const float4 nx1 = xwb[base + 768 + t];

        const float dA0 = __fadd_rn(__fadd_rn(__fmul_rn(cxA, pw0.x), __fmul_rn(cyA, pw0.y)),
                                    __fmul_rn(czA, pw0.z));
        const float sA0 = __fsub_rn(__fadd_rn(scA, pw0.w), __fmul_rn(2.0f, dA0));
        const float dA1 = __fadd_rn(__fadd_rn(__fmul_rn(cxA, pw1.x), __fmul_rn(cyA, pw1.y)),
                                    __fmul_rn(czA, pw1.z));
        const float sA1 = __fsub_rn(__fadd_rn(scA, pw1.w), __fmul_rn(2.0f, dA1));
        const float dB0 = __fadd_rn(__fadd_rn(__fmul_rn(cxB, pw0.x), __fmul_rn(cyB, pw0.y)),
                                    __fmul_rn(czB, pw0.z));
        const float sB0 = __fsub_rn(__fadd_rn(scB, pw0.w), __fmul_rn(2.0f, dB0));
        const float dB1 = __fadd_rn(__fadd_rn(__fmul_rn(cxB, pw1.x), __fmul_rn(cyB, pw1.y)),
                                    __fmul_rn(czB, pw1.z));
        const float sB1 = __fsub_rn(__fadd_rn(scB, pw1.w), __fmul_rn(2.0f, dB1));
        const bool iA0 = (sA0 <= 0.0625f);
        const bool iA1 = (sA1 <= 0.0625f);
        const bool iB0 = (sB0 <= 0.0625f);
        const bool iB1 = (sB1 <= 0.0625f);

        const unsigned long long mA0 = __ballot(iA0);
        const unsigned long long mA1 = __ballot(iA1);
        const unsigned long long mB0 = __ballot(iB0);
        const unsigned long long mB1 = __ballot(iB1);
        if (lane == 0) {
            wcnt[par][0][0][w] = (int)__popcll(mA0);
            wcnt[par][0][1][w] = (int)__popcll(mA1);
            wcnt[par][1][0][w] = (int)__popcll(mB0);
            wcnt[par][1][1][w] = (int)__popcll(mB1);
        }
        __syncthreads();
        const unsigned long long lmask = (1ull << lane) - 1ull;
        {   // query A compaction
            const int c00 = wcnt[par][0][0][0], c01 = wcnt[par][0][0][1];
            const int c02 = wcnt[par][0][0][2], c03 = wcnt[par][0][0][3];
            const int c10 = wcnt[par][0][1][0], c11 = wcnt[par][0][1][1];
            const int c12 = wcnt[par][0][1][2], c13 = wcnt[par][0][1][3];
            int pre0 = foundA;
            if (w > 0) pre0 += c00;
            if (w > 1) pre0 += c01;
            if (w > 2) pre0 += c02;
            const int C0 = c00 + c01 + c02 + c03;
            int pre1 = foundA + C0;
            if (w > 0) pre1 += c10;
            if (w > 1) pre1 += c11;
            if (w > 2) pre1 += c12;
            const int pos0 = pre0 + (int)__popcll(mA0 & lmask);
            const int pos1 = pre1 + (int)__popcll(mA1 & lmask);
            if (iA0 && pos0 < KN) nbr[0][pos0] = base + t;
            if (iA1 && pos1 < KN) nbr[0][pos1] = base + 256 + t;
            foundA += C0 + c10 + c11 + c12 + c13;   // block-uniform
        }
        {   // query B compaction
            const int c00 = wcnt[par][1][0][0], c01 = wcnt[par][1][0][1];
            const int c02 = wcnt[par][1][0][2], c03 = wcnt[par][1][0][3];
            const int c10 = wcnt[par][1][1][0], c11 = wcnt[par][1][1][1];
            const int c12 = wcnt[par][1][1][2], c13 = wcnt[par][1][1][3];
            int pre0 = foundB;
            if (w > 0) pre0 += c00;
            if (w > 1) pre0 += c01;
            if (w > 2) pre0 += c02;
            const int C0 = c00 + c01 + c02 + c03;
            int pre1 = foundB + C0;
            if (w > 0) pre1 += c10;
            if (w > 1) pre1 += c11;
            if (w > 2) pre1 += c12;
            const int pos0 = pre0 + (int)__popcll(mB0 & lmask);
            const int pos1 = pre1 + (int)__popcll(mB1 & lmask);
            if (iB0 && pos0 < KN) nbr[1][pos0] = base + t;
            if (iB1 && pos1 < KN) nbr[1][pos1] = base + 256 + t;
            foundB += C0 + c10 + c11 + c12 + c13;   // block-uniform
        }
        par ^= 1;
        if (foundA >= KN && foundB >= KN) break;
        pw0 = nx0;
        pw1 = nx1;
    }
    __syncthreads();                  // nbr visible to all
    const int cntA = (foundA < KN) ? foundA : KN;
    const int cntB = (foundB < KN) ? foundB : KN;
    const int fstA = (cntA > 0) ? nbr[0][0] : NPTS;
    const int fstB = (cntB > 0) ? nbr[1][0] : NPTS;

    if (t < 2 * KN) {
        const int qq = t >> 5, i = t & 31;
        const int cnt = qq ? cntB : cntA;
        const int fst = qq ? fstB : fstA;
        out1[(size_t)(q0 + qq) * KN + i] = (float)((i < cnt) ? nbr[qq][i] : fst);
    }

    // ---- Phase 1: gather + rel + posenc into XsQ (k=91 is 1.0 for b1) ----
    #pragma unroll
    for (int qq = 0; qq < 2; ++qq) {
        const int k  = t >> 3;
        const int tc = t & 7;
        const int cnt = qq ? cntB : cntA;
        const int fst = qq ? fstB : fstA;
        const float ccx = qq ? cxB : cxA;
        const float ccy = qq ? cyB : cyA;
        const float ccz = qq ? czB : czA;
        const int nidx = (k < cnt) ? nbr[qq][k] : fst;
        const int n = (nidx < NPTS) ? nidx : NPTS - 1;   // JAX OOB gather clamp
        const float4 pw = xwb[n];
        const float rx = pw.x - ccx;
        const float ry = pw.y - ccy;
        const float rz = pw.z - ccz;
        const float* pfr = pf + ((size_t)b * NPTS + n) * 64;

        const float4 f0 = *(const float4*)(pfr + tc * 8);
        const float4 f1 = *(const float4*)(pfr + tc * 8 + 4);
        half8 hv;
        hv[0] = (_Float16)f0.x; hv[1] = (_Float16)f0.y;
        hv[2] = (_Float16)f0.z; hv[3] = (_Float16)f0.w;
        hv[4] = (_Float16)f1.x; hv[5] = (_Float16)f1.y;
        hv[6] = (_Float16)f1.z; hv[7] = (_Float16)f1.w;
        if (qq == 0) *(half8*)&Xs0[k][tc * 8] = hv;
        else         *(half8*)&Xs1[k][tc * 8] = hv;

        // branchless posenc: ch c = 64+cm; cm<3 -> raw rel; 3<=cm<27 ->
        // sin/cos(r * 2^m) via v_sin in revolutions (cos = sin(u+0.25));
        // cm==27 -> 1.0 (bias row); cm>27 -> 0.
        half4v ov;
        #pragma unroll
        for (int j = 0; j < 4; ++j) {
            const int cm = tc * 4 + j;          // 0..31
            const int jj = cm - 3;
            const int d  = jj >> 3;
            const int mm = jj & 7;
            const float rsel = (d == 0) ? rx : ((d == 1) ? ry : rz);
            const float f2 = __int_as_float(0x3E22F983 + ((mm & 3) << 23));
            const float arg = fmaf(rsel, f2, (mm >= 4) ? 0.25f : 0.0f);
#if __has_builtin(__builtin_amdgcn_sinf)
            const float sv = __builtin_amdgcn_sinf(arg);
#else
            const float sv = __sinf(arg * 6.2831853071795864f);
#endif
            float v = (cm < 3) ? ((cm == 0) ? rx : ((cm == 1) ? ry : rz)) : sv;
            v = (cm == 27) ? 1.0f : ((cm > 27) ? 0.0f : v);
            ov[j] = (_Float16)v;
        }
        if (qq == 0) *(half4v*)&Xs0[k][64 + tc * 4] = ov;
        else         *(half4v*)&Xs1[k][64 + tc * 4] = ov;
    }
    __syncthreads();

    f32x4 acc[2][2][4];   // [qq][mt][nt]; lane: ch=(w*4+nt)*16+quad*4+r, pt=mt*16+l15

    // uniform (SGPR) weight bases + per-lane voffset -> saddr-form loads
    const int wu = __builtin_amdgcn_readfirstlane(w);
    const _Float16* __restrict__ w1w = w1p + (size_t)(wu * 4) * 512;
    const _Float16* __restrict__ w2w = w2p + (size_t)(wu * 4) * 512;
    const int lo8 = lane * 8;

    // ---- GEMM1: W1^T as A, Xs{0,1} as B -> acc (b1 via folded row) ----
    #pragma unroll
    for (int qq = 0; qq < 2; ++qq)
        #pragma unroll
        for (int mt = 0; mt < 2; ++mt)
            #pragma unroll
            for (int nt = 0; nt < 4; ++nt)
                acc[qq][mt][nt] = (f32x4){0.f, 0.f, 0.f, 0.f};

    #pragma unroll
    for (int kt = 0; kt < 3; ++kt) {
        const half8 xA0 = *(const half8*)&Xs0[l15][kt * 32 + quad * 8];
        const half8 xA1 = *(const half8*)&Xs0[16 + l15][kt * 32 + quad * 8];
        const half8 xB0 = *(const half8*)&Xs1[l15][kt * 32 + quad * 8];
        const half8 xB1 = *(const half8*)&Xs1[16 + l15][kt * 32 + quad * 8];
        #pragma unroll
        for (int nt = 0; nt < 4; ++nt) {
            const half8 wf = *(const half8*)(w1w + (kt * 16 + nt) * 512 + lo8);
            acc[0][0][nt] = __builtin_amdgcn_mfma_f32_16x16x32_f16(wf, xA0, acc[0][0][nt], 0, 0, 0);
            acc[0][1][nt] = __builtin_amdgcn_mfma_f32_16x16x32_f16(wf, xA1, acc[0][1][nt], 0, 0, 0);
            acc[1][0][nt] = __builtin_amdgcn_mfma_f32_16x16x32_f16(wf, xB0, acc[1][0][nt], 0, 0, 0);
            acc[1][1][nt] = __builtin_amdgcn_mfma_f32_16x16x32_f16(wf, xB1, acc[1][1][nt], 0, 0, 0);
        }
    }

    // ---- LN1 stats on f32 accs (in-register + quad shfl + cross-warp LDS) ----
    float mu[2][2], rs[2][2];
    #pragma unroll
    for (int qq = 0; qq < 2; ++qq)
        #pragma unroll
        for (int mt = 0; mt < 2; ++mt) {
            float s = 0.0f, s2 = 0.0f;
            #pragma unroll
            for (int nt = 0; nt < 4; ++nt)
                #pragma unroll
                for (int r = 0; r < 4; ++r) {
                    const float v = acc[qq][mt][nt][r];
                    s += v;
                    s2 = fmaf(v, v, s2);
                }
            s  += __shfl_xor(s, 16, 64);  s  += __shfl_xor(s, 32, 64);
            s2 += __shfl_xor(s2, 16, 64); s2 += __shfl_xor(s2, 32, 64);
            if (quad == 0) sred[qq][mt][l15][w] = make_float2(s, s2);
        }
    __syncthreads();   // overlay fence (Xs reads done) + sred partials visible
    #pragma unroll
    for (int qq = 0; qq < 2; ++qq)
        #pragma unroll
        for (int mt = 0; mt < 2; ++mt) {
            const float4 pA = *(const float4*)&sred[qq][mt][l15][0];
            const float4 pB = *(const float4*)&sred[qq][mt][l15][2];
            const float S = pA.x + pA.z + pB.x + pB.z;
            const float Q = pA.y + pA.w + pB.y + pB.w;
            const float m_ = S * (1.0f / 256.0f);
            const float var = fmaf(Q, 1.0f / 256.0f, -m_ * m_);
            mu[qq][mt] = m_;
            rs[qq][mt] = __builtin_amdgcn_rsqf(var + 1e-5f);
        }

    // ---- LN1 apply + GeLU in f32, single f16 store into H16 ----
    #pragma unroll
    for (int nt = 0; nt < 4; ++nt) {
        const int chb = (w * 4 + nt) * 16 + quad * 4;
        const half4v g4h  = *(const half4v*)&g1h[chb];
        const half4v be4h = *(const half4v*)&be1h[chb];
        #pragma unroll
        for (int qq = 0; qq < 2; ++qq)
            #pragma unroll
            for (int mt = 0; mt < 2; ++mt) {
                half4v h;
                #pragma unroll
                for (int r = 0; r < 4; ++r) {
                    const float A = (float)g4h[r] * rs[qq][mt];
                    const float y = fmaf(acc[qq][mt][nt][r] - mu[qq][mt], A, (float)be4h[r]);
                    h[r] = (_Float16)gelu_tanh(y);
                }
                if (qq == 0) *(half4v*)&H16a[mt * 16 + l15][chb] = h;
                else         *(half4v*)&H16b[mt * 16 + l15][chb] = h;
            }
    }
    __syncthreads();   // H16 ready for GEMM2 B-reads

    // ---- GEMM2: W2^T as A, H{a,b} as B ----
    #pragma unroll
    for (int qq = 0; qq < 2; ++qq)
        #pragma unroll
        for (int mt = 0; mt < 2; ++mt)
            #pragma unroll
            for (int nt = 0; nt < 4; ++nt)
                acc[qq][mt][nt] = (f32x4){0.f, 0.f, 0.f, 0.f};

    #pragma unroll
    for (int kt = 0; kt < 8; ++kt) {
        const half8 hA0 = *(const half8*)&H16a[l15][kt * 32 + quad * 8];
        const half8 hA1 = *(const half8*)&H16a[16 + l15][kt * 32 + quad * 8];
        const half8 hB0 = *(const half8*)&H16b[l15][kt * 32 + quad * 8];
        const half8 hB1 = *(const half8*)&H16b[16 + l15][kt * 32 + quad * 8];
        #pragma unroll
        for (int nt = 0; nt < 4; ++nt) {
            const half8 wf = *(const half8*)(w2w + (kt * 16 + nt) * 512 + lo8);
            acc[0][0][nt] = __builtin_amdgcn_mfma_f32_16x16x32_f16(wf, hA0, acc[0][0][nt], 0, 0, 0);
            acc[0][1][nt] = __builtin_amdgcn_mfma_f32_16x16x32_f16(wf, hA1, acc[0][1][nt], 0, 0, 0);
            acc[1][0][nt] = __builtin_amdgcn_mfma_f32_16x16x32_f16(wf, hB0, acc[1][0][nt], 0, 0, 0);
            acc[1][1][nt] = __builtin_amdgcn_mfma_f32_16x16x32_f16(wf, hB1, acc[1][1][nt], 0, 0, 0);
        }
    }

    // ---- +b2, LN2 stats on f32 accs ----
    #pragma unroll
    for (int nt = 0; nt < 4; ++nt) {
        const f32x4 bv = *(const f32x4*)&b2[(w * 4 + nt) * 16 + quad * 4];
        #pragma unroll
        for (int qq = 0; qq < 2; ++qq)
            #pragma unroll
            for (int mt = 0; mt < 2; ++mt)
                #pragma unroll
                for (int r = 0; r < 4; ++r)
                    acc[qq][mt][nt][r] += bv[r];
    }
    #pragma unroll
    for (int qq = 0; qq < 2; ++qq)
        #pragma unroll
        for (int mt = 0; mt < 2; ++mt) {
            float s = 0.0f, s2 = 0.0f;
            #pragma unroll
            for (int nt = 0; nt < 4; ++nt)
                #pragma unroll
                for (int r = 0; r < 4; ++r) {
                    const float v = acc[qq][mt][nt][r];
                    s += v;
                    s2 = fmaf(v, v, s2);
                }
            s  += __shfl_xor(s, 16, 64);  s  += __shfl_xor(s, 32, 64);
            s2 += __shfl_xor(s2, 16, 64); s2 += __shfl_xor(s2, 32, 64);
            if (quad == 0) sred[qq][mt][l15][w] = make_float2(s, s2);
        }
    __syncthreads();   // ALL H16 B-reads done (in-place store safe) + partials
    #pragma unroll
    for (int qq = 0; qq < 2; ++qq)
        #pragma unroll
        for (int mt = 0; mt < 2; ++mt) {
            const float4 pA = *(const float4*)&sred[qq][mt][l15][0];
            const float4 pB = *(const float4*)&sred[qq][mt][l15][2];
            const float S = pA.x + pA.z + pB.x + pB.z;
            const float Q = pA.y + pA.w + pB.y + pB.w;
            const float m_ = S * (1.0f / 256.0f);
            const float var = fmaf(Q, 1.0f / 256.0f, -m_ * m_);
            mu[qq][mt] = m_;
            rs[qq][mt] = __builtin_amdgcn_rsqf(var + 1e-5f);
        }

    // ---- LN2 apply (no activation), f16 store into H16 ----
    #pragma unroll
    for (int nt = 0; nt < 4; ++nt) {
        const int chb = (w * 4 + nt) * 16 + quad * 4;
        const half4v g4h  = *(const half4v*)&g2h[chb];
        const half4v be4h = *(const half4v*)&be2h[chb];
        #pragma unroll
        for (int qq = 0; qq < 2; ++qq)
            #pragma unroll
            for (int mt = 0; mt < 2; ++mt) {
                half4v h;
                #pragma unroll
                for (int r = 0; r < 4; ++r) {
                    const float A = (float)g4h[r] * rs[qq][mt];
                    h[r] = (_Float16)fmaf(acc[qq][mt][nt][r] - mu[qq][mt], A, (float)be4h[r]);
                }
                if (qq == 0) *(half4v*)&H16a[mt * 16 + l15][chb] = h;
                else         *(half4v*)&H16b[mt * 16 + l15][chb] = h;
            }
    }
    __syncthreads();

    // ---- Phase 6: packed max over 32 points, all 256 threads (2 queries) ----
    {
        const int qq = t >> 7;
        const int tt = t & 127;
        const _Float16* Hf = qq ? &H16b[0][0] : &H16a[0][0];
        half2t mx = *(const half2t*)(Hf + 2 * tt);
        #pragma unroll
        for (int r = 1; r < KN; ++r) {
            const half2t v = *(const half2t*)(Hf + r * HSTR + 2 * tt);
            mx = __builtin_elementwise_max(mx, v);
        }
        float2 o2;
        o2.x = (float)mx[0];
        o2.y = (float)mx[1];
        *(float2*)&out0[(size_t)(q0 + qq) * C + 2 * tt] = o2;
    }
}

extern "C" void kernel_launch(void* const* d_in, const int* in_sizes, int n_in,
                              void* d_out, int out_size, void* d_ws, size_t ws_size,
                              hipStream_t stream) {
    const float* xyz = (const float*)d_in[0];
    const float* pf  = (const float*)d_in[1];
    const float* ctr = (const float*)d_in[2];
    const float* W1  = (const float*)d_in[3];
    const float* b1  = (const float*)d_in[4];
    const float* g1  = (const float*)d_in[5];
    const float* be1 = (const float*)d_in[6];
    const float* W2  = (const float*)d_in[7];
    const float* b2  = (const float*)d_in[8];
    const float* g2  = (const float*)d_in[9];
    const float* be2 = (const float*)d_in[10];

    float* out = (float*)d_out;
    _Float16* wp = (_Float16*)d_ws;
    float4* xyzw = (float4*)(wp + WP_ELEMS);   // 180224 B offset, 16-aligned; +2.06 MB

    prep_kernel<<<(WP_ELEMS + XYZW_ELEMS) / 256, 256, 0, stream>>>(W1, b1, W2, xyz, wp, xyzw);
    encoder_fused<<<NQ / 2, 256, 0, stream>>>(xyzw, pf, ctr,
                                              g1, be1, b2, g2, be2,
                                              wp, wp + W1P_ELEMS,
                                              out, out + PF_ELEMS);
}